// Round 1
// baseline (1837.733 us; speedup 1.0000x reference)
//
#include <hip/hip_runtime.h>
#include <cstdint>
#include <cstddef>

// Problem dims (fixed by the reference)
constexpr int L_ = 6, B_ = 4, S_ = 1024, D_ = 1024, H_ = 16, FF_ = 4096;
constexpr int D3_ = 3 * D_;   // 3072
constexpr int HD_ = D_ / H_;  // 64

typedef float f32x4 __attribute__((ext_vector_type(4)));
typedef __bf16 bf16x8 __attribute__((ext_vector_type(8)));
typedef unsigned short u16;
typedef u16 u16x4 __attribute__((ext_vector_type(4)));
typedef u16 u16x8 __attribute__((ext_vector_type(8)));

__device__ __forceinline__ u16 f2bf(float f) {
    union { float f; uint32_t u; } v; v.f = f;
    uint32_t r = v.u + 0x7FFFu + ((v.u >> 16) & 1u);   // RNE
    return (u16)(r >> 16);
}

// ---------------------------------------------------------------------------
// Weight prep: fp32 W[K][N]  ->  bf16 W^T[N][K]   (one-time per call, HBM-bound)
// grid: (N/64, K/64), block 256
// ---------------------------------------------------------------------------
__global__ __launch_bounds__(256) void cvt_transpose(
    const float* __restrict__ W, u16* __restrict__ WT, int K, int N)
{
    __shared__ float tile[64][65];
    const int tid = threadIdx.x;
    const int bn = blockIdx.x * 64, bk = blockIdx.y * 64;
    #pragma unroll
    for (int i = 0; i < 16; ++i) {
        int idx = i * 256 + tid;
        int r = idx >> 6, c = idx & 63;
        tile[r][c] = W[(size_t)(bk + r) * N + bn + c];
    }
    __syncthreads();
    #pragma unroll
    for (int i = 0; i < 16; ++i) {
        int idx = i * 256 + tid;
        int r = idx >> 6, c = idx & 63;
        WT[(size_t)(bn + r) * K + bk + c] = f2bf(tile[c][r]);
    }
}

// ---------------------------------------------------------------------------
// V transpose: qkv[B*S][3D] (v at col 2D)  ->  vt[(b*H+h)*HD + hd][S]  (bf16)
// grid: (S/64, B*H), block 256
// ---------------------------------------------------------------------------
__global__ __launch_bounds__(256) void vt_transpose(
    const u16* __restrict__ qkv, u16* __restrict__ vt)
{
    __shared__ u16 tile[64][72];
    const int tid = threadIdx.x;
    const int s0 = blockIdx.x * 64, bh = blockIdx.y;
    const int b = bh >> 4, h = bh & 15;
    #pragma unroll
    for (int i = 0; i < 2; ++i) {
        int idx = tid + i * 256;
        int r = idx >> 3, c8 = (idx & 7) * 8;
        u16x8 v = *(const u16x8*)(qkv + ((size_t)(b * S_ + s0 + r)) * D3_ + 2 * D_ + h * 64 + c8);
        #pragma unroll
        for (int j = 0; j < 8; ++j) tile[c8 + j][r] = v[j];
    }
    __syncthreads();
    #pragma unroll
    for (int i = 0; i < 2; ++i) {
        int idx = tid + i * 256;
        int r = idx >> 3, c8 = (idx & 7) * 8;
        u16x8 v;
        #pragma unroll
        for (int j = 0; j < 8; ++j) v[j] = tile[r][c8 + j];
        *(u16x8*)(vt + ((size_t)(bh * 64 + r)) * S_ + s0 + c8) = v;
    }
}

// ---------------------------------------------------------------------------
// LayerNorm row kernel: fp32 X row (1024) -> bf16 xn.  grid: B*S, block 256.
// ---------------------------------------------------------------------------
__global__ __launch_bounds__(256) void ln_kernel(
    const float* __restrict__ X, const float* __restrict__ g,
    const float* __restrict__ bp, u16* __restrict__ out)
{
    const int row = blockIdx.x, tid = threadIdx.x;
    const float* xr = X + (size_t)row * D_;
    f32x4 v = *(const f32x4*)(xr + tid * 4);
    float s  = v[0] + v[1] + v[2] + v[3];
    float s2 = v[0]*v[0] + v[1]*v[1] + v[2]*v[2] + v[3]*v[3];
    #pragma unroll
    for (int off = 32; off >= 1; off >>= 1) {
        s  += __shfl_down(s,  off);
        s2 += __shfl_down(s2, off);
    }
    __shared__ float red[8];
    const int lane = tid & 63, wid = tid >> 6;
    if (lane == 0) { red[wid] = s; red[4 + wid] = s2; }
    __syncthreads();
    s  = red[0] + red[1] + red[2] + red[3];
    s2 = red[4] + red[5] + red[6] + red[7];
    float mean = s * (1.f / D_);
    float var  = s2 * (1.f / D_) - mean * mean;     // == mean((x-m)^2)
    float rstd = rsqrtf(var + 1e-5f);
    f32x4 gv = *(const f32x4*)(g  + tid * 4);
    f32x4 bv = *(const f32x4*)(bp + tid * 4);
    u16x4 o4;
    #pragma unroll
    for (int r = 0; r < 4; ++r) o4[r] = f2bf((v[r] - mean) * rstd * gv[r] + bv[r]);
    *(u16x4*)(out + (size_t)row * D_ + tid * 4) = o4;
}

// ---------------------------------------------------------------------------
// MFMA GEMM: C[M][N] = A[M][K] * B, with B given as B^T[N][K] (both bf16).
// 128x128 tile, BK=32, 4 waves (2x2), 4x4 16x16x32 fragments per wave.
// XOR-swizzled LDS ((row&3)<<4 on 64B rows) -> conflict-free ds_read_b128.
// 2-phase register prefetch hides global latency under the 16-MFMA phase.
// MODE: 0=+bias->bf16 (QKV), 1=+bias,pad-mask,X+= (out-proj),
//       2=+bias,GELU->bf16 (FC1), 3=+bias,X+= (FC2)
// ---------------------------------------------------------------------------
template<int MODE>
__global__ __launch_bounds__(256) void gemm_bt(
    const u16* __restrict__ A, const u16* __restrict__ BT,
    const float* __restrict__ bias,
    u16* __restrict__ Cb, float* __restrict__ X,
    const int* __restrict__ lengths,
    int M, int N, int K)
{
    __shared__ __align__(16) u16 lA[128 * 32];
    __shared__ __align__(16) u16 lB[128 * 32];
    const int tid = threadIdx.x;
    const int lane = tid & 63;
    const int grp = lane >> 4, l15 = lane & 15;
    const int wid = tid >> 6;
    const int wm = wid >> 1, wn = wid & 1;
    const int m0 = blockIdx.y * 128, n0 = blockIdx.x * 128;

    const int srow = tid >> 2, sgg = tid & 3;          // staging: 4x16B per 64B row
    const size_t aoff = (size_t)(m0 + srow) * K + sgg * 8;
    const size_t boff = (size_t)(n0 + srow) * K + sgg * 8;
    char* lAw = (char*)lA + srow * 64 + ((sgg * 16) ^ ((srow & 3) << 4));
    char* lBw = (char*)lB + srow * 64 + ((sgg * 16) ^ ((srow & 3) << 4));

    f32x4 acc[4][4] = {};
    bf16x8 ra0 = *(const bf16x8*)(A  + aoff);
    bf16x8 ra1 = *(const bf16x8*)(A  + aoff + (size_t)64 * K);
    bf16x8 rb0 = *(const bf16x8*)(BT + boff);
    bf16x8 rb1 = *(const bf16x8*)(BT + boff + (size_t)64 * K);

    for (int kk = 0; kk < K; kk += 32) {
        __syncthreads();
        *(bf16x8*)lAw          = ra0;
        *(bf16x8*)(lAw + 4096) = ra1;
        *(bf16x8*)lBw          = rb0;
        *(bf16x8*)(lBw + 4096) = rb1;
        __syncthreads();
        if (kk + 32 < K) {   // prefetch next K-step (consumed next iteration)
            ra0 = *(const bf16x8*)(A  + aoff + kk + 32);
            ra1 = *(const bf16x8*)(A  + aoff + (size_t)64 * K + kk + 32);
            rb0 = *(const bf16x8*)(BT + boff + kk + 32);
            rb1 = *(const bf16x8*)(BT + boff + (size_t)64 * K + kk + 32);
        }
        bf16x8 af[4], bfr[4];
        #pragma unroll
        for (int mf = 0; mf < 4; ++mf) {
            int r = wm * 64 + mf * 16 + l15;
            af[mf] = *(const bf16x8*)((const char*)lA + r * 64 + ((grp * 16) ^ ((r & 3) << 4)));
        }
        #pragma unroll
        for (int nf = 0; nf < 4; ++nf) {
            int r = wn * 64 + nf * 16 + l15;
            bfr[nf] = *(const bf16x8*)((const char*)lB + r * 64 + ((grp * 16) ^ ((r & 3) << 4)));
        }
        #pragma unroll
        for (int mf = 0; mf < 4; ++mf)
            #pragma unroll
            for (int nf = 0; nf < 4; ++nf)
                acc[mf][nf] = __builtin_amdgcn_mfma_f32_16x16x32_bf16(af[mf], bfr[nf], acc[mf][nf], 0, 0, 0);
    }

    // Epilogue.  C/D frag: col = lane&15, row = (lane>>4)*4 + reg  [HW-verified]
    #pragma unroll
    for (int mf = 0; mf < 4; ++mf) {
        int row_g = m0 + wm * 64 + mf * 16 + grp * 4;
        #pragma unroll
        for (int nf = 0; nf < 4; ++nf) {
            int col_g = n0 + wn * 64 + nf * 16 + l15;
            float bv = bias[col_g];
            f32x4 v = acc[mf][nf];
            if constexpr (MODE == 0) {
                #pragma unroll
                for (int r = 0; r < 4; ++r)
                    Cb[(size_t)(row_g + r) * N + col_g] = f2bf(v[r] + bv);
            } else if constexpr (MODE == 2) {
                #pragma unroll
                for (int r = 0; r < 4; ++r) {
                    float t = v[r] + bv;
                    float ge = 0.5f * t * (1.f + erff(t * 0.70710678118654752f));
                    Cb[(size_t)(row_g + r) * N + col_g] = f2bf(ge);
                }
            } else if constexpr (MODE == 1) {
                #pragma unroll
                for (int r = 0; r < 4; ++r) {
                    int row = row_g + r;
                    int bidx = row >> 10, sp = row & 1023;
                    float add = (sp >= lengths[bidx]) ? 0.f : (v[r] + bv);
                    X[(size_t)row * N + col_g] += add;
                }
            } else {
                #pragma unroll
                for (int r = 0; r < 4; ++r)
                    X[(size_t)(row_g + r) * N + col_g] += v[r] + bv;
            }
        }
    }
}

// ---------------------------------------------------------------------------
// Flash attention with rel_bias + causal + key-padding masks.
// grid: (S/64 q-tiles, B*H), block 256 (4 waves x 16 q-rows).
// Swapped QK^T (scores^T = K · Q^T) makes the softmax reduction lane-local and
// the P fragments feed the PV MFMA B-operand directly (k-slot bijection).
// O^T = V^T · P^T accumulated in fp32.
// ---------------------------------------------------------------------------
__global__ __launch_bounds__(256) void attn_kernel(
    const u16* __restrict__ qkv,     // [B*S][3D] bf16 (q | k | v)
    const u16* __restrict__ vt,      // [(b*H+h)*64 + hd][S] bf16
    const float* __restrict__ rel_bias, // [H][S][S] fp32
    const int* __restrict__ lengths,
    u16* __restrict__ obuf)          // [B*S][D] bf16
{
    __shared__ __align__(16) char kls[64 * 128];  // K tile  [kpos][hd], swizzled
    __shared__ __align__(16) char vls[64 * 128];  // V^T tile [hd][kpos], swizzled
    const int tid = threadIdx.x, lane = tid & 63, wid = tid >> 6;
    const int grp = lane >> 4, l15 = lane & 15;
    const int qt = blockIdx.x, bh = blockIdx.y;
    const int b = bh >> 4, h = bh & 15;
    const int len = lengths[b];
    const int qrow = qt * 64 + wid * 16 + l15;

    bf16x8 qf[2];
    {
        const u16* qp = qkv + ((size_t)(b * S_ + qrow)) * D3_ + h * 64 + grp * 8;
        qf[0] = *(const bf16x8*)qp;
        qf[1] = *(const bf16x8*)(qp + 32);
    }
    f32x4 oacc[4] = {};
    float m_run = -INFINITY, lsum = 0.f;
    int kt_end = (len + 63) >> 6;
    if (qt + 1 < kt_end) kt_end = qt + 1;   // causal trim

    for (int kt = 0; kt < kt_end; ++kt) {
        __syncthreads();
        #pragma unroll
        for (int i = 0; i < 2; ++i) {
            int id2 = tid + i * 256;
            int r = id2 >> 3, gg = id2 & 7;
            int sw = (r & 7) << 4;
            bf16x8 kv = *(const bf16x8*)(qkv + ((size_t)(b * S_ + kt * 64 + r)) * D3_ + D_ + h * 64 + gg * 8);
            *(bf16x8*)(kls + r * 128 + ((gg * 16) ^ sw)) = kv;
            bf16x8 vv = *(const bf16x8*)(vt + ((size_t)(bh * 64 + r)) * S_ + kt * 64 + gg * 8);
            *(bf16x8*)(vls + r * 128 + ((gg * 16) ^ sw)) = vv;
        }
        __syncthreads();

        // scores^T fragments: sf[f] covers kpos f*16..f*16+15 (rows), q (cols)
        f32x4 sf[4] = {};
        #pragma unroll
        for (int f = 0; f < 4; ++f) {
            int r = f * 16 + l15;
            int sw = (r & 7) << 4;
            #pragma unroll
            for (int t = 0; t < 2; ++t) {
                bf16x8 af = *(const bf16x8*)(kls + r * 128 + (((t * 32 + grp * 8) * 2) ^ sw));
                sf[f] = __builtin_amdgcn_mfma_f32_16x16x32_bf16(af, qf[t], sf[f], 0, 0, 0);
            }
        }
        // scale + rel_bias + causal + padding, then online softmax (per q = l15)
        float p[4][4];
        float tmax = -INFINITY;
        #pragma unroll
        for (int f = 0; f < 4; ++f) {
            f32x4 bi = *(const f32x4*)(rel_bias + ((size_t)h * S_ + qrow) * S_ + kt * 64 + f * 16 + grp * 4);
            #pragma unroll
            for (int r = 0; r < 4; ++r) {
                int kp = kt * 64 + f * 16 + grp * 4 + r;
                bool valid = (kp <= qrow) && (kp < len);
                float sv = valid ? fmaf(sf[f][r], 0.125f, bi[r]) : -INFINITY;
                p[f][r] = sv;
                tmax = fmaxf(tmax, sv);
            }
        }
        tmax = fmaxf(tmax, __shfl_xor(tmax, 16));
        tmax = fmaxf(tmax, __shfl_xor(tmax, 32));
        float m_new = fmaxf(m_run, tmax);
        float alpha = expf(m_run - m_new);   // 0 on first tile (m_run = -inf)
        float psum = 0.f;
        #pragma unroll
        for (int f = 0; f < 4; ++f)
            #pragma unroll
            for (int r = 0; r < 4; ++r) {
                float e = expf(p[f][r] - m_new);   // masked -> exp(-inf) = 0
                p[f][r] = e; psum += e;
            }
        psum += __shfl_xor(psum, 16);
        psum += __shfl_xor(psum, 32);
        lsum = lsum * alpha + psum;
        m_run = m_new;
        #pragma unroll
        for (int fo = 0; fo < 4; ++fo) {
            oacc[fo][0] *= alpha; oacc[fo][1] *= alpha;
            oacc[fo][2] *= alpha; oacc[fo][3] *= alpha;
        }
        // O^T += V^T · P^T ; k-slot bijection g(grp,j)=grp*4+(j&3)+16*(j>>2)
        #pragma unroll
        for (int t = 0; t < 2; ++t) {
            union { u16 u[8]; bf16x8 v; } pb;
            #pragma unroll
            for (int j = 0; j < 4; ++j) {
                pb.u[j]     = f2bf(p[2 * t][j]);
                pb.u[4 + j] = f2bf(p[2 * t + 1][j]);
            }
            #pragma unroll
            for (int fo = 0; fo < 4; ++fo) {
                int r = fo * 16 + l15;          // hd row of V^T
                int sw = (r & 7) << 4;
                union { u16x4 h4[2]; bf16x8 v; } av;
                av.h4[0] = *(const u16x4*)(vls + r * 128 + ((t * 64 + grp * 8)      ^ sw));
                av.h4[1] = *(const u16x4*)(vls + r * 128 + ((t * 64 + grp * 8 + 32) ^ sw));
                oacc[fo] = __builtin_amdgcn_mfma_f32_16x16x32_bf16(av.v, pb.v, oacc[fo], 0, 0, 0);
            }
        }
    }
    float inv = 1.f / lsum;
    #pragma unroll
    for (int fo = 0; fo < 4; ++fo)
        #pragma unroll
        for (int r = 0; r < 4; ++r) {
            int hd = fo * 16 + grp * 4 + r;
            obuf[((size_t)(b * S_) + qrow) * D_ + h * 64 + hd] = f2bf(oacc[fo][r] * inv);
        }
}

// ---------------------------------------------------------------------------
extern "C" void kernel_launch(void* const* d_in, const int* in_sizes, int n_in,
                              void* d_out, int out_size, void* d_ws, size_t ws_size,
                              hipStream_t stream)
{
    const float* x_in     = (const float*)d_in[0];
    const int*   lengths  = (const int*)d_in[1];
    const float* rel_bias = (const float*)d_in[2];
    const float* ln1_g    = (const float*)d_in[3];
    const float* ln1_b    = (const float*)d_in[4];
    const float* qkv_w    = (const float*)d_in[5];
    const float* qkv_b    = (const float*)d_in[6];
    const float* out_w    = (const float*)d_in[7];
    const float* out_b    = (const float*)d_in[8];
    const float* ln2_g    = (const float*)d_in[9];
    const float* ln2_b    = (const float*)d_in[10];
    const float* fc1_w    = (const float*)d_in[11];
    const float* fc1_b    = (const float*)d_in[12];
    const float* fc2_w    = (const float*)d_in[13];
    const float* fc2_b    = (const float*)d_in[14];
    float* X = (float*)d_out;     // running residual state, fp32

    char* ws = (char*)d_ws;
    size_t off = 0;
    auto alloc = [&](size_t bytes) {
        char* p = ws + off;
        off = (off + bytes + 255) & ~(size_t)255;
        return p;
    };
    u16* wT_qkv = (u16*)alloc((size_t)D3_ * D_ * 2);      // 6.3 MB (per-layer reuse)
    u16* wT_out = (u16*)alloc((size_t)D_ * D_ * 2);       // 2.1 MB
    u16* wT_fc1 = (u16*)alloc((size_t)FF_ * D_ * 2);      // 8.4 MB
    u16* wT_fc2 = (u16*)alloc((size_t)D_ * FF_ * 2);      // 8.4 MB
    u16* xn     = (u16*)alloc((size_t)B_ * S_ * D_ * 2);  // 8.4 MB
    u16* qkvb   = (u16*)alloc((size_t)B_ * S_ * D3_ * 2); // 25.2 MB
    u16* vtb    = (u16*)alloc((size_t)B_ * H_ * HD_ * S_ * 2); // 8.4 MB
    u16* ob     = (u16*)alloc((size_t)B_ * S_ * D_ * 2);  // 8.4 MB
    u16* h1     = (u16*)alloc((size_t)B_ * S_ * FF_ * 2); // 33.6 MB

    const int M = B_ * S_;  // 4096

    hipMemcpyAsync(X, x_in, (size_t)M * D_ * sizeof(float),
                   hipMemcpyDeviceToDevice, stream);

    for (int i = 0; i < L_; ++i) {
        // --- one-time weight convert+transpose (fp32 -> bf16 W^T) ---
        cvt_transpose<<<dim3(D3_ / 64, D_ / 64), 256, 0, stream>>>(
            qkv_w + (size_t)i * D_ * D3_, wT_qkv, D_, D3_);
        cvt_transpose<<<dim3(D_ / 64, D_ / 64), 256, 0, stream>>>(
            out_w + (size_t)i * D_ * D_, wT_out, D_, D_);
        cvt_transpose<<<dim3(FF_ / 64, D_ / 64), 256, 0, stream>>>(
            fc1_w + (size_t)i * D_ * FF_, wT_fc1, D_, FF_);
        cvt_transpose<<<dim3(D_ / 64, FF_ / 64), 256, 0, stream>>>(
            fc2_w + (size_t)i * FF_ * D_, wT_fc2, FF_, D_);

        // --- attention sub-block ---
        ln_kernel<<<M, 256, 0, stream>>>(X, ln1_g + i * D_, ln1_b + i * D_, xn);
        gemm_bt<0><<<dim3(D3_ / 128, M / 128), 256, 0, stream>>>(
            xn, wT_qkv, qkv_b + (size_t)i * D3_, qkvb, nullptr, nullptr, M, D3_, D_);
        vt_transpose<<<dim3(S_ / 64, B_ * H_), 256, 0, stream>>>(qkvb, vtb);
        attn_kernel<<<dim3(S_ / 64, B_ * H_), 256, 0, stream>>>(
            qkvb, vtb, rel_bias, lengths, ob);
        gemm_bt<1><<<dim3(D_ / 128, M / 128), 256, 0, stream>>>(
            ob, wT_out, out_b + (size_t)i * D_, nullptr, X, lengths, M, D_, D_);

        // --- feed-forward sub-block ---
        ln_kernel<<<M, 256, 0, stream>>>(X, ln2_g + i * D_, ln2_b + i * D_, xn);
        gemm_bt<2><<<dim3(FF_ / 128, M / 128), 256, 0, stream>>>(
            xn, wT_fc1, fc1_b + (size_t)i * FF_, h1, nullptr, nullptr, M, FF_, D_);
        gemm_bt<3><<<dim3(D_ / 128, M / 128), 256, 0, stream>>>(
            h1, wT_fc2, fc2_b + (size_t)i * D_, nullptr, X, nullptr, M, D_, FF_);
    }
}